// Round 4
// baseline (194.055 us; speedup 1.0000x reference)
//
#include <hip/hip_runtime.h>

typedef __attribute__((ext_vector_type(8))) short short8;
typedef __attribute__((ext_vector_type(16))) float f32x16;

#define N_IMG 32
#define C_IN 32
#define C_OUT 32
#define HH 224
#define WW 224
#define HW (HH * WW)
#define TILE_H 8
#define TILE_W 32
#define IN_H (TILE_H + 2)   // 10
#define IN_W (TILE_W + 2)   // 34
#define PIX_STRIDE 80       // bytes/pixel in LDS: 64B data (32ch bf16) + 16B pad (5x16B -> conflict-free)
#define N_HBLK (HH / TILE_H)  // 28
#define N_WBLK (WW / TILE_W)  // 7
#define N_TILES (N_IMG * N_HBLK * N_WBLK)  // 6272
#define NCHUNK (IN_H * IN_W * 4)  // 1360 staging chunks (8ch x 16B each)
#define NIT 6                     // ceil(1360/256)

// fp32 -> bf16 bits, round-to-nearest-even
__device__ __forceinline__ short f2bf(float f) {
    unsigned u = __float_as_uint(f);
    u += 0x7FFFu + ((u >> 16) & 1u);
    return (short)(u >> 16);
}

// launch_bounds(256,3): known-good, spill-free codegen. (256,5) spilled wfrag (R2).
// Occupancy is NOT the limiter (R3: grid 768->1280 changed nothing at 29% occ);
// staging MLP is: this version issues all ~48 loads/thread before any vmcnt drain.
__global__ __launch_bounds__(256, 3)
void conv3x3_kernel(const float* __restrict__ X, const float* __restrict__ Wt,
                    const float* __restrict__ Bias, float* __restrict__ Y) {
    __shared__ __align__(16) char xtile[IN_H * IN_W * PIX_STRIDE];  // 27,200 B

    const int tid = threadIdx.x;
    const int lane = tid & 63;
    const int wid = tid >> 6;      // wave 0..3
    const int col = lane & 31;     // A: out-channel row; B/C: pixel col
    const int khalf = lane >> 5;   // k-half of the MFMA K=16 slice

    // --- W fragments in registers (A operand: M=32 k_out, K=16 c-slice) ---
    short8 wfrag[18];
#pragma unroll
    for (int rs = 0; rs < 9; ++rs) {
#pragma unroll
        for (int ch = 0; ch < 2; ++ch) {
            short8 f;
#pragma unroll
            for (int j = 0; j < 8; ++j) {
                int c = ch * 16 + khalf * 8 + j;
                f[j] = f2bf(Wt[(col * C_IN + c) * 9 + rs]);  // W[k_out][c][r][s]
            }
            wfrag[rs * 2 + ch] = f;
        }
    }

    // --- Bias in C-fragment order: row(k_out) = (i&3) + 8*(i>>2) + 4*khalf ---
    f32x16 biasv;
#pragma unroll
    for (int i = 0; i < 16; ++i)
        biasv[i] = Bias[(i & 3) + 8 * (i >> 2) + 4 * khalf];

    for (int tile = blockIdx.x; tile < N_TILES; tile += gridDim.x) {
        int wblk = tile % N_WBLK;
        int t2 = tile / N_WBLK;
        int hblk = t2 % N_HBLK;
        int n = t2 / N_HBLK;
        int h0 = hblk * TILE_H, w0 = wblk * TILE_W;

        // ===== Phase A: issue ALL staging loads into registers (no LDS, no waits).
        // 48 independent global loads/thread in flight -> one latency exposure/tile
        // instead of 5.3 serialized drains (R3 lesson).
        float vv[NIT][8];
#pragma unroll
        for (int it = 0; it < NIT; ++it) {
            int cid = tid + it * 256;
            int icol = cid % IN_W;
            int t = cid / IN_W;
            int irow = t % IN_H;
            int cc = t / IN_H;  // channel chunk 0..3
            int h_in = h0 - 1 + irow;
            int w_in = w0 - 1 + icol;
            bool valid = (cid < NCHUNK) &&
                         (unsigned)h_in < (unsigned)HH && (unsigned)w_in < (unsigned)WW;
            const float* p = X + ((n * C_IN + cc * 8) * HH + h_in) * WW + w_in;
#pragma unroll
            for (int j = 0; j < 8; ++j)
                vv[it][j] = valid ? p[j * HW] : 0.f;
        }

        __syncthreads();  // prev tile's readers done (also drains the loads above)

        // ===== Phase B: convert + LDS write
#pragma unroll
        for (int it = 0; it < NIT; ++it) {
            int cid = tid + it * 256;
            if (cid < NCHUNK) {
                int icol = cid % IN_W;
                int t = cid / IN_W;
                int irow = t % IN_H;
                int cc = t / IN_H;
                short8 o;
#pragma unroll
                for (int j = 0; j < 8; ++j)
                    o[j] = f2bf(vv[it][j]);
                *(short8*)(xtile + (irow * IN_W + icol) * PIX_STRIDE + cc * 16) = o;
            }
        }
        __syncthreads();

        // ===== Compute: each wave owns 2 tile rows; 18 MFMAs per row =====
#pragma unroll
        for (int nb = 0; nb < 2; ++nb) {
            int tr = wid * 2 + nb;
            f32x16 acc = biasv;  // bias folded into accumulator init
#pragma unroll
            for (int rs = 0; rs < 9; ++rs) {
                int r = rs / 3, s = rs - 3 * r;
                int pixbase = ((tr + r) * IN_W + col + s) * PIX_STRIDE + khalf * 16;
#pragma unroll
                for (int ch = 0; ch < 2; ++ch) {
                    short8 bfrag = *(const short8*)(xtile + pixbase + ch * 32);
                    acc = __builtin_amdgcn_mfma_f32_32x32x16_bf16(
                        wfrag[rs * 2 + ch], bfrag, acc, 0, 0, 0);
                }
            }
            int ybase = (n * C_OUT * HH + (h0 + tr)) * WW + w0 + col;
#pragma unroll
            for (int i = 0; i < 16; ++i) {
                int ko = (i & 3) + 8 * (i >> 2) + 4 * khalf;
                Y[ybase + ko * HW] = acc[i];
            }
        }
    }
}

extern "C" void kernel_launch(void* const* d_in, const int* in_sizes, int n_in,
                              void* d_out, int out_size, void* d_ws, size_t ws_size,
                              hipStream_t stream) {
    const float* X = (const float*)d_in[0];
    const float* W = (const float*)d_in[1];
    const float* B = (const float*)d_in[2];
    float* Y = (float*)d_out;
    conv3x3_kernel<<<dim3(1280), dim3(256), 0, stream>>>(X, W, B, Y);
}

// Round 5
// 138.491 us; speedup vs baseline: 1.4012x; 1.4012x over previous
//
#include <hip/hip_runtime.h>

typedef __attribute__((ext_vector_type(8))) short short8;
typedef __attribute__((ext_vector_type(16))) float f32x16;

#define N_IMG 32
#define C_IN 32
#define C_OUT 32
#define HH 224
#define WW 224
#define HW (HH * WW)
#define TILE_H 8
#define TILE_W 32
#define IN_H (TILE_H + 2)   // 10
#define IN_W (TILE_W + 2)   // 34
#define PIX_STRIDE 80       // 64B data (32ch bf16) + 16B pad; 5x16B -> conflict-free b128
#define TILE_BYTES (IN_H * IN_W * PIX_STRIDE)  // 27,200
#define N_HBLK (HH / TILE_H)  // 28
#define N_WBLK (WW / TILE_W)  // 7
#define N_TILES (N_IMG * N_HBLK * N_WBLK)  // 6272
#define NCHUNK (IN_H * IN_W * 4)  // 1360 staging chunks (8ch each)
#define NIT 6                     // ceil(1360/256)

// fp32 -> bf16 bits, round-to-nearest-even
__device__ __forceinline__ short f2bf(float f) {
    unsigned u = __float_as_uint(f);
    u += 0x7FFFu + ((u >> 16) & 1u);
    return (short)(u >> 16);
}

// (256,2): 256-VGPR cap so the cross-tile staging regs (vv=48) + wfrag (72) fit
// WITHOUT spill (R4: (256,3) spilled vv -> +136MB scratch HBM traffic).
// 2 blocks/CU (LDS 2x27.2KB dbuf x2 blocks = 108.8KB); overlap, not occupancy,
// is the lever (R3: 5 blocks changed nothing).
__global__ __launch_bounds__(256, 2)
void conv3x3_kernel(const float* __restrict__ X, const float* __restrict__ Wt,
                    const float* __restrict__ Bias, float* __restrict__ Y) {
    __shared__ __align__(16) char xtile[2][TILE_BYTES];  // 54,400 B

    const int tid = threadIdx.x;
    const int lane = tid & 63;
    const int wid = tid >> 6;      // wave 0..3
    const int col = lane & 31;     // A: out-channel row; B/C: pixel col
    const int khalf = lane >> 5;   // k-half of the MFMA K=16 slice

    // --- W fragments in registers (A operand: M=32 k_out, K=16 c-slice) ---
    short8 wfrag[18];
#pragma unroll
    for (int rs = 0; rs < 9; ++rs) {
#pragma unroll
        for (int ch = 0; ch < 2; ++ch) {
            short8 f;
#pragma unroll
            for (int j = 0; j < 8; ++j) {
                int c = ch * 16 + khalf * 8 + j;
                f[j] = f2bf(Wt[(col * C_IN + c) * 9 + rs]);  // W[k_out][c][r][s]
            }
            wfrag[rs * 2 + ch] = f;
        }
    }

    // --- Bias in C-fragment order: row(k_out) = (i&3) + 8*(i>>2) + 4*khalf ---
    f32x16 biasv;
#pragma unroll
    for (int i = 0; i < 16; ++i)
        biasv[i] = Bias[(i & 3) + 8 * (i >> 2) + 4 * khalf];

    // --- Per-thread staging geometry (tile-invariant, hoisted) ---
    // chunk cid -> (irow, icol, cc); goff = offset from X(n, h0-1, w0-1) base.
    // cid >= NCHUNK poisoned via irow=9999 -> valid=false -> zero-write lands in pad.
    int s_irow[NIT], s_icol[NIT], s_goff[NIT], s_lds[NIT];
#pragma unroll
    for (int it = 0; it < NIT; ++it) {
        int cid = tid + it * 256;
        int icol = cid % IN_W;
        int t = cid / IN_W;
        int irow = t % IN_H;
        int cc = t / IN_H;  // channel chunk 0..4 (4 = overflow -> pad bytes)
        s_irow[it] = (cid < NCHUNK) ? irow : 9999;
        s_icol[it] = icol;
        s_goff[it] = (cc * 8 * HH + irow) * WW + icol;
        s_lds[it] = (irow * IN_W + icol) * PIX_STRIDE + cc * 16;
    }

    const int stride = gridDim.x;
    float vv[NIT][8];

    // ===== Prologue: stage first tile into buf0 (one-time serialized latency) =====
    int tile = blockIdx.x;
    {
        int wblk = tile % N_WBLK;
        int t2 = tile / N_WBLK;
        int n = t2 / N_HBLK;
        int h0 = (t2 % N_HBLK) * TILE_H, w0 = wblk * TILE_W;
        const float* xb = X + n * C_IN * HW + (h0 - 1) * WW + (w0 - 1);
#pragma unroll
        for (int it = 0; it < NIT; ++it) {
#pragma unroll
            for (int j = 0; j < 8; ++j) vv[it][j] = 0.f;
            int h_in = h0 - 1 + s_irow[it];
            int w_in = w0 - 1 + s_icol[it];
            if ((unsigned)h_in < (unsigned)HH && (unsigned)w_in < (unsigned)WW) {
                const float* p = xb + s_goff[it];
#pragma unroll
                for (int j = 0; j < 8; ++j) vv[it][j] = p[j * HW];
            }
        }
#pragma unroll
        for (int it = 0; it < NIT; ++it) {
            short8 o;
#pragma unroll
            for (int j = 0; j < 8; ++j) o[j] = f2bf(vv[it][j]);
            *(short8*)(xtile[0] + s_lds[it]) = o;
        }
    }
    __syncthreads();

    // ===== Main loop: issue loads(t+1) || compute(t) || write(t+1); 1 barrier/tile =====
    int cur = 0;
    for (; tile < N_TILES; tile += stride) {
        int nxt = tile + stride;
        bool has_next = nxt < N_TILES;  // block-uniform

        // Phase 1: issue next tile's global loads into registers (no waits here;
        // vmcnt drain happens at Phase 3's first use, after the MFMA phase).
        if (has_next) {
            int wblk = nxt % N_WBLK;
            int t2 = nxt / N_WBLK;
            int n = t2 / N_HBLK;
            int h0 = (t2 % N_HBLK) * TILE_H, w0 = wblk * TILE_W;
            const float* xb = X + n * C_IN * HW + (h0 - 1) * WW + (w0 - 1);
#pragma unroll
            for (int it = 0; it < NIT; ++it) {
#pragma unroll
                for (int j = 0; j < 8; ++j) vv[it][j] = 0.f;
                int h_in = h0 - 1 + s_irow[it];
                int w_in = w0 - 1 + s_icol[it];
                if ((unsigned)h_in < (unsigned)HH && (unsigned)w_in < (unsigned)WW) {
                    const float* p = xb + s_goff[it];
#pragma unroll
                    for (int j = 0; j < 8; ++j) vv[it][j] = p[j * HW];
                }
            }
        }

        // Phase 2: compute current tile from xtile[cur]
        {
            int wblk = tile % N_WBLK;
            int t2 = tile / N_WBLK;
            int n = t2 / N_HBLK;
            int h0 = (t2 % N_HBLK) * TILE_H, w0 = wblk * TILE_W;
            const char* xb_lds = xtile[cur];
#pragma unroll
            for (int nb = 0; nb < 2; ++nb) {
                int tr = wid * 2 + nb;
                f32x16 acc = biasv;  // bias folded into accumulator init
#pragma unroll
                for (int rs = 0; rs < 9; ++rs) {
                    int r = rs / 3, s = rs - 3 * r;
                    int pixbase = ((tr + r) * IN_W + col + s) * PIX_STRIDE + khalf * 16;
#pragma unroll
                    for (int ch = 0; ch < 2; ++ch) {
                        short8 bfrag = *(const short8*)(xb_lds + pixbase + ch * 32);
                        acc = __builtin_amdgcn_mfma_f32_32x32x16_bf16(
                            wfrag[rs * 2 + ch], bfrag, acc, 0, 0, 0);
                    }
                }
                int ybase = (n * C_OUT * HH + (h0 + tr)) * WW + w0 + col;
#pragma unroll
                for (int i = 0; i < 16; ++i) {
                    int ko = (i & 3) + 8 * (i >> 2) + 4 * khalf;
                    Y[ybase + ko * HW] = acc[i];
                }
            }
        }

        // Phase 3: convert + write next tile into the other buffer.
        // Safe without a pre-barrier: xtile[cur^1] was last read in the PREVIOUS
        // iteration's Phase 2, which the previous iteration's barrier fenced.
        if (has_next) {
            char* xw = xtile[cur ^ 1];
#pragma unroll
            for (int it = 0; it < NIT; ++it) {
                short8 o;
#pragma unroll
                for (int j = 0; j < 8; ++j) o[j] = f2bf(vv[it][j]);
                *(short8*)(xw + s_lds[it]) = o;
            }
        }
        __syncthreads();
        cur ^= 1;
    }
}

extern "C" void kernel_launch(void* const* d_in, const int* in_sizes, int n_in,
                              void* d_out, int out_size, void* d_ws, size_t ws_size,
                              hipStream_t stream) {
    const float* X = (const float*)d_in[0];
    const float* W = (const float*)d_in[1];
    const float* B = (const float*)d_in[2];
    float* Y = (float*)d_out;
    // 512 blocks = exactly 2 resident/CU (LDS-limited); ~12 tiles per block
    conv3x3_kernel<<<dim3(512), dim3(256), 0, stream>>>(X, W, B, Y);
}

// Round 6
// 103.188 us; speedup vs baseline: 1.8806x; 1.3421x over previous
//
#include <hip/hip_runtime.h>

typedef __attribute__((ext_vector_type(4))) float float4v;
typedef __attribute__((ext_vector_type(8))) short short8;
typedef __attribute__((ext_vector_type(16))) float f32x16;

#define C_IN 32
#define C_OUT 32
#define HH 224
#define WW 224
#define HW (HH * WW)
#define STRIPE 28                 // output rows per block; 224 = 8 stripes x 32 imgs = 256 blocks
#define RING_PX 226               // w = -1 .. 224 (halo columns at px 0 and 225)
#define PIX_STRIDE 80             // 64B data (32ch bf16) + 16B pad; 5x16B coprime 8 -> conflict-free b128
#define ROW_BYTES (RING_PX * PIX_STRIDE)  // 18,080
#define NTHR 512

// fp32 -> bf16 bits, round-to-nearest-even
__device__ __forceinline__ short f2bf(float f) {
    unsigned u = __float_as_uint(f);
    u += 0x7FFFu + ((u >> 16) & 1u);
    return (short)(u >> 16);
}
// pack two bf16 (even ch in low half) into one dword
__device__ __forceinline__ unsigned pack2(float e, float o) {
    return (unsigned)(unsigned short)f2bf(e) | ((unsigned)(unsigned short)f2bf(o) << 16);
}

// Rolling row-window conv: block = (image, 28-row stripe), full 224 width.
// X is read once per stripe as coalesced float4 row streams; 3-row bf16 LDS ring.
// waves_per_eu(2,2): pin allocator at 2 waves/EU (256 VGPR cap) so it stops
// targeting 4/EU and spilling the staged rows (R2/R4/R5 lesson).
__global__ __launch_bounds__(NTHR) __attribute__((amdgpu_waves_per_eu(2, 2)))
void conv3x3_rows(const float* __restrict__ X, const float* __restrict__ Wt,
                  const float* __restrict__ Bias, float* __restrict__ Y) {
    __shared__ __align__(16) char ring0[ROW_BYTES];
    __shared__ __align__(16) char ring1[ROW_BYTES];
    __shared__ __align__(16) char ring2[ROW_BYTES];   // 54,240 B total (static-safe)

    const int tid = threadIdx.x;
    const int lane = tid & 63;
    const int wid = tid >> 6;      // wave 0..7
    const int col = lane & 31;     // A: out-channel; B/C: pixel col
    const int khalf = lane >> 5;   // K-half of MFMA K=16 slice

    // --- W fragments (A operand: M=32 k_out, K=16 c-slice), same as prior rounds ---
    short8 wfrag[18];
#pragma unroll
    for (int rs = 0; rs < 9; ++rs) {
#pragma unroll
        for (int ch = 0; ch < 2; ++ch) {
            short8 f;
#pragma unroll
            for (int j = 0; j < 8; ++j) {
                int c = ch * 16 + khalf * 8 + j;
                f[j] = f2bf(Wt[(col * C_IN + c) * 9 + rs]);  // W[k_out][c][r][s]
            }
            wfrag[rs * 2 + ch] = f;
        }
    }

    // --- Bias in C-fragment order: row(k_out) = (i&3) + 8*(i>>2) + 4*khalf ---
    f32x16 biasv;
#pragma unroll
    for (int i = 0; i < 16; ++i)
        biasv[i] = Bias[(i & 3) + 8 * (i >> 2) + 4 * khalf];

    // --- Staging geometry: unit u = w4*16 + cp (cp = channel-pair 0..15, w4 = 0..55).
    // Consecutive lanes -> consecutive cp: LDS b32 writes hit 16 consecutive words
    // (2-way bank alias only = free); global float4 reads still form 256B/ch runs.
    const int cp0 = tid & 15, w40 = tid >> 4;         // unit0 = tid (56*16=896 units total)
    const int t1 = tid + NTHR;
    const bool has1 = (tid < 896 - NTHR);             // threads 0..383 take a second unit
    const int cp1 = t1 & 15, w41 = t1 >> 4;
    const int ge0 = (2 * cp0) * HW + 4 * w40;         // float offsets from (n, hh) row base
    const int go0 = ge0 + HW;
    const int ge1 = (2 * cp1) * HW + 4 * w41;
    const int go1 = ge1 + HW;

    const int bid = blockIdx.x;
    const int n = bid >> 3;
    const int h1 = (bid & 7) * STRIPE;
    const float* Xn = X + n * C_IN * HW;

    float4v e0, o0, e1, o1;
    const short8 z8 = {0, 0, 0, 0, 0, 0, 0, 0};

#define LOAD_ROW(hh) do {                                          \
        const float* rp = Xn + (hh) * WW;                          \
        e0 = *(const float4v*)(rp + ge0);                          \
        o0 = *(const float4v*)(rp + go0);                          \
        if (has1) {                                                \
            e1 = *(const float4v*)(rp + ge1);                      \
            o1 = *(const float4v*)(rp + go1);                      \
        }                                                          \
    } while (0)

#define WRITE_ROW(sb) do {                                         \
        char* wb0 = (sb) + (1 + 4 * w40) * PIX_STRIDE + cp0 * 4;   \
        *(unsigned*)(wb0                  ) = pack2(e0[0], o0[0]); \
        *(unsigned*)(wb0 +     PIX_STRIDE ) = pack2(e0[1], o0[1]); \
        *(unsigned*)(wb0 + 2 * PIX_STRIDE ) = pack2(e0[2], o0[2]); \
        *(unsigned*)(wb0 + 3 * PIX_STRIDE ) = pack2(e0[3], o0[3]); \
        if (has1) {                                                \
            char* wb1 = (sb) + (1 + 4 * w41) * PIX_STRIDE + cp1 * 4; \
            *(unsigned*)(wb1                  ) = pack2(e1[0], o1[0]); \
            *(unsigned*)(wb1 +     PIX_STRIDE ) = pack2(e1[1], o1[1]); \
            *(unsigned*)(wb1 + 2 * PIX_STRIDE ) = pack2(e1[2], o1[2]); \
            *(unsigned*)(wb1 + 3 * PIX_STRIDE ) = pack2(e1[3], o1[3]); \
        }                                                          \
        if (tid < 8) {  /* zero the two w-halo pixels (px 0 and 225) */ \
            int px = (tid < 4) ? 0 : (RING_PX - 1);                \
            *(short8*)((sb) + px * PIX_STRIDE + (tid & 3) * 16) = z8; \
        }                                                          \
    } while (0)

#define ZERO_ROW(sb) do {                                          \
        for (int i = tid; i < ROW_BYTES / 16; i += NTHR)           \
            *(short8*)((sb) + i * 16) = z8;                        \
    } while (0)

    // ===== Prologue: fill ring with rows h1-1, h1, h1+1 =====
#pragma unroll
    for (int j = 0; j < 3; ++j) {
        int hh = h1 - 1 + j;
        char* sb = (j == 0) ? ring0 : (j == 1) ? ring1 : ring2;
        if (hh >= 0 && hh < HH) {   // block-uniform
            LOAD_ROW(hh);
            WRITE_ROW(sb);
        } else {
            ZERO_ROW(sb);
        }
    }
    __syncthreads();

    // ===== Main loop: rA = row h-1, rB = h, rC = h+1; write h+2 over rA =====
    char *rA = ring0, *rB = ring1, *rC = ring2;
    const int pcol = col * PIX_STRIDE + khalf * 16;

    for (int h = h1; h < h1 + STRIPE; ++h) {
        const int hh = h + 2;
        const bool do_pref = (hh <= h1 + STRIPE);   // last needed row = h1+STRIPE
        const bool validrow = do_pref && (hh < HH); // block-uniform

        // Phase 1: issue next row's global loads (waits land in Phase 4, after MFMA)
        if (validrow) LOAD_ROW(hh);

        // Phase 2: compute output row h; wave w owns px [32w, 32w+32)
        if (wid < 7) {
            const int px0 = wid * 32;
            f32x16 acc = biasv;   // bias folded into accumulator init
            const int pb = px0 * PIX_STRIDE + pcol;
#pragma unroll
            for (int rs = 0; rs < 9; ++rs) {
                const int r = rs / 3, s = rs - 3 * r;
                const char* rb = (r == 0) ? rA : (r == 1) ? rB : rC;
                const int addr = pb + s * PIX_STRIDE;  // ring px = (w + s-1) + 1 = px0+col+s
#pragma unroll
                for (int ch = 0; ch < 2; ++ch) {
                    short8 bfrag = *(const short8*)(rb + addr + ch * 32);
                    acc = __builtin_amdgcn_mfma_f32_32x32x16_bf16(
                        wfrag[rs * 2 + ch], bfrag, acc, 0, 0, 0);
                }
            }
            const int ybase = n * C_OUT * HW + h * WW + px0 + col;
#pragma unroll
            for (int i = 0; i < 16; ++i) {
                int ko = (i & 3) + 8 * (i >> 2) + 4 * khalf;
                Y[ybase + ko * HW] = acc[i];
            }
        }

        // Phase 3: all reads of rA done before it is overwritten
        __syncthreads();

        // Phase 4: convert + write row h+2 into the expired slot
        if (validrow) {
            WRITE_ROW(rA);
        } else if (do_pref) {
            ZERO_ROW(rA);   // image bottom edge (stripe 7)
        }
        __syncthreads();

        // rotate ring
        char* t = rA; rA = rB; rB = rC; rC = t;
    }
#undef LOAD_ROW
#undef WRITE_ROW
#undef ZERO_ROW
}

extern "C" void kernel_launch(void* const* d_in, const int* in_sizes, int n_in,
                              void* d_out, int out_size, void* d_ws, size_t ws_size,
                              hipStream_t stream) {
    const float* X = (const float*)d_in[0];
    const float* W = (const float*)d_in[1];
    const float* B = (const float*)d_in[2];
    float* Y = (float*)d_out;
    // 256 blocks = 32 images x 8 stripes = exactly 1 block per CU
    conv3x3_rows<<<dim3(256), dim3(NTHR), 0, stream>>>(X, W, B, Y);
}